// Round 2
// baseline (520.065 us; speedup 1.0000x reference)
//
#include <hip/hip_runtime.h>

#define NCOLS 107
#define ROWS_PER_GROUP 4                 // 4 rows * 107 cols = 428 floats = 107 f4, 16B-aligned
#define GROUP_F4 NCOLS                   // 107 f4 per group per array
#define THREADS 256

typedef float f4 __attribute__((ext_vector_type(4)));

// ---- compile-time column classification -----------------------------------
// CAT slices: (1,10)(10,26)(27,34)(34,49)(49,55)(55,60)(60,62)(65,107)
// MSE cols: 0, 26, 62, 63, 64
__device__ __host__ __forceinline__ constexpr int slice_of(int col) {
    return (col >= 1  && col < 10) ? 0 :
           (col >= 10 && col < 26) ? 1 :
           (col >= 27 && col < 34) ? 2 :
           (col >= 34 && col < 49) ? 3 :
           (col >= 49 && col < 55) ? 4 :
           (col >= 55 && col < 60) ? 5 :
           (col >= 60 && col < 62) ? 6 :
           (col >= 65)             ? 7 : -1;   // -1 = MSE col
}
__device__ __host__ __forceinline__ constexpr int slice_last(int sid) {
    return sid == 0 ?  9 : sid == 1 ? 25 : sid == 2 ? 33 : sid == 3 ? 48 :
           sid == 4 ? 54 : sid == 5 ? 59 : sid == 6 ? 61 : 106;
}

// One element at linear index L within the 4-row group. Everything about L is
// compile-time: row-local column, MSE-vs-CE, slice id, and whether this column
// completes its slice (flush log into lse, reset the slice sum register).
// Template (not pragma-unroll) so s[sid] indexing is GUARANTEED static —
// runtime-indexed arrays go to scratch (rule #20).
template<int L>
__device__ __forceinline__ void elem(float d, float t, float (&s)[8],
                                     float& mse, float& dot, float& lse) {
    constexpr int col = L % NCOLS;
    constexpr int sid = slice_of(col);
    if constexpr (sid < 0) {
        float df = d - t;
        mse += df * df;                       // MSE cols {0,26,62,63,64}
    } else {
        s[sid] += __expf(d);                  // slice sum for LSE
        dot = __builtin_fmaf(d, t, dot);      // one-hot: sum d*t = logit[label]
        if constexpr (col == slice_last(sid)) {
            lse += __logf(s[sid]);            // slice complete -> flush
            s[sid] = 0.0f;
        }
    }
}

// Fully unrolled walk over the 107 f4 chunks of one 4-row group (both arrays).
// Straight-line basic block: compiler batches loads ahead of use (bounded by
// the launch_bounds VGPR cap below).
template<int C>
__device__ __forceinline__ void walk(const f4* __restrict__ gd,
                                     const f4* __restrict__ gt,
                                     float (&s)[8],
                                     float& mse, float& dot, float& lse) {
    if constexpr (C < GROUP_F4) {
        f4 dv = gd[C];                        // offsets C*16 <= 1696: fold into imm
        f4 tv = gt[C];
        elem<4 * C + 0>(dv[0], tv[0], s, mse, dot, lse);
        elem<4 * C + 1>(dv[1], tv[1], s, mse, dot, lse);
        elem<4 * C + 2>(dv[2], tv[2], s, mse, dot, lse);
        elem<4 * C + 3>(dv[3], tv[3], s, mse, dot, lse);
        walk<C + 1>(gd, gt, s, mse, dot, lse);
    }
}

// min 2 waves/EU -> VGPR cap 256: keeps the 428-wide unrolled block from
// ballooning register allocation to 1-wave occupancy.
__global__ __launch_bounds__(THREADS, 2) void multiloss_main(
        const float* __restrict__ dec, const float* __restrict__ tru,
        float2* __restrict__ ws, int ngroups) {
    int g = blockIdx.x * THREADS + threadIdx.x;   // one 4-row group per thread
    float mse = 0.0f, dot = 0.0f, lse = 0.0f;
    float s[8] = {0.0f, 0.0f, 0.0f, 0.0f, 0.0f, 0.0f, 0.0f, 0.0f};
    if (g < ngroups) {
        const f4* gd = (const f4*)dec + (size_t)g * GROUP_F4;  // byte off g*1712, 16B-aligned
        const f4* gt = (const f4*)tru + (size_t)g * GROUP_F4;
        walk<0>(gd, gt, s, mse, dot, lse);
    }
    float ce = lse - dot;
    // 64-lane shuffle reduction; one ws slot per wave, no atomics
#pragma unroll
    for (int off = 32; off > 0; off >>= 1) {
        mse += __shfl_down(mse, off, 64);
        ce  += __shfl_down(ce,  off, 64);
    }
    int lane  = threadIdx.x & 63;
    int gwave = (blockIdx.x * THREADS + threadIdx.x) >> 6;
    if (lane == 0)
        ws[gwave] = make_float2(mse, ce);
}

__global__ __launch_bounds__(256) void multiloss_fin(
        const float2* __restrict__ ws, float* __restrict__ out,
        int nslots, float invN) {
    float m = 0.0f, c = 0.0f;
    for (int i = threadIdx.x; i < nslots; i += 256) {
        float2 v = ws[i];
        m += v.x; c += v.y;
    }
#pragma unroll
    for (int off = 32; off > 0; off >>= 1) {
        m += __shfl_down(m, off, 64);
        c += __shfl_down(c, off, 64);
    }
    __shared__ float sm[4], sc[4];
    int wid  = threadIdx.x >> 6;
    int lane = threadIdx.x & 63;
    if (lane == 0) { sm[wid] = m; sc[wid] = c; }
    __syncthreads();
    if (threadIdx.x == 0) {
        float mse = (sm[0] + sm[1] + sm[2] + sm[3]) * invN;
        float ce  = (sc[0] + sc[1] + sc[2] + sc[3]) * invN;
        out[0] = mse + ce;
        out[1] = mse;
        out[2] = ce;
    }
}

extern "C" void kernel_launch(void* const* d_in, const int* in_sizes, int n_in,
                              void* d_out, int out_size, void* d_ws, size_t ws_size,
                              hipStream_t stream) {
    const float* dec = (const float*)d_in[0];
    const float* tru = (const float*)d_in[1];
    int nrows   = in_sizes[0] / NCOLS;          // 524288
    int ngroups = nrows / ROWS_PER_GROUP;       // 131072 (exact at BATCH=524288)
    int nblocks = (ngroups + THREADS - 1) / THREADS;   // 512
    int nwaves  = nblocks * (THREADS / 64);            // 2048 slots, 16 KB ws
    float2* ws = (float2*)d_ws;
    multiloss_main<<<nblocks, THREADS, 0, stream>>>(dec, tru, ws, ngroups);
    multiloss_fin<<<1, 256, 0, stream>>>(ws, (float*)d_out, nwaves,
                                         1.0f / (float)nrows);
}

// Round 3
// 465.366 us; speedup vs baseline: 1.1175x; 1.1175x over previous
//
#include <hip/hip_runtime.h>

#define NCOLS 107
#define ROWS_PER_GROUP 4     // 4 rows * 107 cols = 428 floats = 107 f4, 16B-aligned
#define GROUP_F4 NCOLS       // 107 f4 per group per array
#define THREADS 256
#define BATCH_N 8            // f4-chunks per pipeline batch (8 d + 8 t = 16 loads in flight)
#define NFULL 13             // 13 full batches = 104 chunks
#define TAILC 104            // tail batch: chunks 104..106 (3 chunks)

typedef float f4 __attribute__((ext_vector_type(4)));

// ---- compile-time column classification -----------------------------------
// CAT slices: (1,10)(10,26)(27,34)(34,49)(49,55)(55,60)(60,62)(65,107)
// MSE cols: 0, 26, 62, 63, 64
__device__ __host__ __forceinline__ constexpr int slice_of(int col) {
    return (col >= 1  && col < 10) ? 0 :
           (col >= 10 && col < 26) ? 1 :
           (col >= 27 && col < 34) ? 2 :
           (col >= 34 && col < 49) ? 3 :
           (col >= 49 && col < 55) ? 4 :
           (col >= 55 && col < 60) ? 5 :
           (col >= 60 && col < 62) ? 6 :
           (col >= 65)             ? 7 : -1;   // -1 = MSE col
}
__device__ __host__ __forceinline__ constexpr int slice_last(int sid) {
    return sid == 0 ?  9 : sid == 1 ? 25 : sid == 2 ? 33 : sid == 3 ? 48 :
           sid == 4 ? 54 : sid == 5 ? 59 : sid == 6 ? 61 : 106;
}

// One element at linear index L within the 4-row group. col/sid/flush-point all
// compile-time; s[sid] indexing guaranteed static (rule #20: no scratch).
template<int L>
__device__ __forceinline__ void elem(float d, float t, float (&s)[8],
                                     float& mse, float& dot, float& lse) {
    constexpr int col = L % NCOLS;
    constexpr int sid = slice_of(col);
    if constexpr (sid < 0) {
        float df = d - t;
        mse += df * df;                       // MSE cols {0,26,62,63,64}
    } else {
        s[sid] += __expf(d);                  // slice sum for LSE
        dot = __builtin_fmaf(d, t, dot);      // one-hot: sum d*t = logit[label]
        if constexpr (col == slice_last(sid)) {
            lse += __logf(s[sid]);            // slice complete -> flush
            s[sid] = 0.0f;
        }
    }
}

// ---- explicit MLP pipeline --------------------------------------------------
// Round-2 post-mortem: compiler serialized the 214 loads (VGPR=36, 315 cy/load).
// Here loads are batched into register arrays (static indices via templates) and
// pinned above the previous batch's compute with one coarse sched_barrier(0)
// per batch, so 16 loads stay in flight across each compute phase.

template<int C0, int K, int N>
__device__ __forceinline__ void load_rec(const f4* __restrict__ gd,
                                         const f4* __restrict__ gt,
                                         f4 (&d)[BATCH_N], f4 (&t)[BATCH_N]) {
    if constexpr (K < N) {
        d[K] = gd[C0 + K];                    // offsets (C0+K)*16 fold into imm
        t[K] = gt[C0 + K];
        load_rec<C0, K + 1, N>(gd, gt, d, t);
    }
}

template<int C0, int K, int N>
__device__ __forceinline__ void proc_rec(const f4 (&d)[BATCH_N],
                                         const f4 (&t)[BATCH_N], float (&s)[8],
                                         float& mse, float& dot, float& lse) {
    if constexpr (K < N) {
        elem<4 * (C0 + K) + 0>(d[K][0], t[K][0], s, mse, dot, lse);
        elem<4 * (C0 + K) + 1>(d[K][1], t[K][1], s, mse, dot, lse);
        elem<4 * (C0 + K) + 2>(d[K][2], t[K][2], s, mse, dot, lse);
        elem<4 * (C0 + K) + 3>(d[K][3], t[K][3], s, mse, dot, lse);
        proc_rec<C0, K + 1, N>(d, t, s, mse, dot, lse);
    }
}

// stage<B>: dc/tc hold batch B (loads already issued). Issue batch B+1 (or the
// 3-chunk tail), fence the scheduler, process batch B, recurse.
template<int B>
__device__ __forceinline__ void stage(const f4* __restrict__ gd,
                                      const f4* __restrict__ gt,
                                      f4 (&dc)[BATCH_N], f4 (&tc)[BATCH_N],
                                      float (&s)[8],
                                      float& mse, float& dot, float& lse) {
    constexpr int C0 = B * BATCH_N;
    f4 dn[BATCH_N], tn[BATCH_N];
    if constexpr (B + 1 < NFULL) {
        load_rec<(B + 1) * BATCH_N, 0, BATCH_N>(gd, gt, dn, tn);
    } else {
        load_rec<TAILC, 0, 3>(gd, gt, dn, tn);
    }
    __builtin_amdgcn_sched_barrier(0);        // loads stay above this compute
    proc_rec<C0, 0, BATCH_N>(dc, tc, s, mse, dot, lse);
    if constexpr (B + 1 < NFULL) {
        stage<B + 1>(gd, gt, dn, tn, s, mse, dot, lse);
    } else {
        proc_rec<TAILC, 0, 3>(dn, tn, s, mse, dot, lse);   // tail, no prefetch
    }
}

// min 2 waves/EU -> VGPR cap 256 (grid supplies exactly 8 waves/CU).
__global__ __launch_bounds__(THREADS, 2) void multiloss_main(
        const float* __restrict__ dec, const float* __restrict__ tru,
        float2* __restrict__ ws, int ngroups) {
    int g = blockIdx.x * THREADS + threadIdx.x;   // one 4-row group per thread
    float mse = 0.0f, dot = 0.0f, lse = 0.0f;
    float s[8] = {0.0f, 0.0f, 0.0f, 0.0f, 0.0f, 0.0f, 0.0f, 0.0f};
    if (g < ngroups) {
        const f4* gd = (const f4*)dec + (size_t)g * GROUP_F4;  // byte off g*1712
        const f4* gt = (const f4*)tru + (size_t)g * GROUP_F4;
        f4 d0[BATCH_N], t0[BATCH_N];
        load_rec<0, 0, BATCH_N>(gd, gt, d0, t0);  // prologue: batch 0 in flight
        stage<0>(gd, gt, d0, t0, s, mse, dot, lse);
    }
    float ce = lse - dot;
    // 64-lane shuffle reduction; one ws slot per wave, no atomics
#pragma unroll
    for (int off = 32; off > 0; off >>= 1) {
        mse += __shfl_down(mse, off, 64);
        ce  += __shfl_down(ce,  off, 64);
    }
    int lane  = threadIdx.x & 63;
    int gwave = (blockIdx.x * THREADS + threadIdx.x) >> 6;
    if (lane == 0)
        ws[gwave] = make_float2(mse, ce);
}

__global__ __launch_bounds__(256) void multiloss_fin(
        const float2* __restrict__ ws, float* __restrict__ out,
        int nslots, float invN) {
    float m = 0.0f, c = 0.0f;
    for (int i = threadIdx.x; i < nslots; i += 256) {
        float2 v = ws[i];
        m += v.x; c += v.y;
    }
#pragma unroll
    for (int off = 32; off > 0; off >>= 1) {
        m += __shfl_down(m, off, 64);
        c += __shfl_down(c, off, 64);
    }
    __shared__ float sm[4], sc[4];
    int wid  = threadIdx.x >> 6;
    int lane = threadIdx.x & 63;
    if (lane == 0) { sm[wid] = m; sc[wid] = c; }
    __syncthreads();
    if (threadIdx.x == 0) {
        float mse = (sm[0] + sm[1] + sm[2] + sm[3]) * invN;
        float ce  = (sc[0] + sc[1] + sc[2] + sc[3]) * invN;
        out[0] = mse + ce;
        out[1] = mse;
        out[2] = ce;
    }
}

extern "C" void kernel_launch(void* const* d_in, const int* in_sizes, int n_in,
                              void* d_out, int out_size, void* d_ws, size_t ws_size,
                              hipStream_t stream) {
    const float* dec = (const float*)d_in[0];
    const float* tru = (const float*)d_in[1];
    int nrows   = in_sizes[0] / NCOLS;          // 524288
    int ngroups = nrows / ROWS_PER_GROUP;       // 131072 (exact at BATCH=524288)
    int nblocks = (ngroups + THREADS - 1) / THREADS;   // 512
    int nwaves  = nblocks * (THREADS / 64);            // 2048 slots, 16 KB ws
    float2* ws = (float2*)d_ws;
    multiloss_main<<<nblocks, THREADS, 0, stream>>>(dec, tru, ws, ngroups);
    multiloss_fin<<<1, 256, 0, stream>>>(ws, (float*)d_out, nwaves,
                                         1.0f / (float)nrows);
}

// Round 4
// 463.816 us; speedup vs baseline: 1.1213x; 1.0033x over previous
//
#include <hip/hip_runtime.h>

#define NCOLS 107
#define ROWS_PER_GROUP 4     // 4 rows * 107 cols = 428 floats = 107 f4, 16B-aligned
#define GROUP_F4 NCOLS       // 107 f4 per group per array
#define THREADS 256
#define BN 4                 // f4-chunks per batch (4 d + 4 t = 8 loads)
#define NBAT 27              // 26 full batches + tail of 3 chunks (26*4+3 = 107)

typedef float f4 __attribute__((ext_vector_type(4)));

__device__ __host__ __forceinline__ constexpr int bstart(int b) { return b * BN; }
__device__ __host__ __forceinline__ constexpr int blen(int b) {
    return b < NBAT - 1 ? BN : (GROUP_F4 - BN * (NBAT - 1));   // tail = 3
}

// ---- compile-time column classification -----------------------------------
// CAT slices: (1,10)(10,26)(27,34)(34,49)(49,55)(55,60)(60,62)(65,107)
// MSE cols: 0, 26, 62, 63, 64
__device__ __host__ __forceinline__ constexpr int slice_of(int col) {
    return (col >= 1  && col < 10) ? 0 :
           (col >= 10 && col < 26) ? 1 :
           (col >= 27 && col < 34) ? 2 :
           (col >= 34 && col < 49) ? 3 :
           (col >= 49 && col < 55) ? 4 :
           (col >= 55 && col < 60) ? 5 :
           (col >= 60 && col < 62) ? 6 :
           (col >= 65)             ? 7 : -1;   // -1 = MSE col
}
__device__ __host__ __forceinline__ constexpr int slice_last(int sid) {
    return sid == 0 ?  9 : sid == 1 ? 25 : sid == 2 ? 33 : sid == 3 ? 48 :
           sid == 4 ? 54 : sid == 5 ? 59 : sid == 6 ? 61 : 106;
}

// One element at linear index L within the 4-row group. col/sid/flush-point all
// compile-time; s[sid] indexing guaranteed static (rule #20: no scratch).
template<int L>
__device__ __forceinline__ void elem(float d, float t, float (&s)[8],
                                     float& mse, float& dot, float& lse) {
    constexpr int col = L % NCOLS;
    constexpr int sid = slice_of(col);
    if constexpr (sid < 0) {
        float df = d - t;
        mse += df * df;                       // MSE cols {0,26,62,63,64}
    } else {
        s[sid] += __expf(d);                  // slice sum for LSE
        dot = __builtin_fmaf(d, t, dot);      // one-hot: sum d*t = logit[label]
        if constexpr (col == slice_last(sid)) {
            lse += __logf(s[sid]);            // slice complete -> flush
            s[sid] = 0.0f;
        }
    }
}

// ---- depth-3 software pipeline ---------------------------------------------
// Round-3 post-mortem: depth-1 (VGPR=88) left each wave stalled ~500 cy/batch
// on vmcnt with only 16 loads in flight. Here 3 batches (24 loads) stay in
// flight while a 4th is processed; buffers rotate via template recursion so
// every array index is static.

template<int B, int K = 0>
__device__ __forceinline__ void bload(const f4* __restrict__ gd,
                                      const f4* __restrict__ gt,
                                      f4 (&d)[BN], f4 (&t)[BN]) {
    if constexpr (K < blen(B)) {
        d[K] = gd[bstart(B) + K];             // offsets fold into imm
        t[K] = gt[bstart(B) + K];
        bload<B, K + 1>(gd, gt, d, t);
    }
}

template<int B, int K = 0>
__device__ __forceinline__ void bproc(const f4 (&d)[BN], const f4 (&t)[BN],
                                      float (&s)[8],
                                      float& mse, float& dot, float& lse) {
    if constexpr (K < blen(B)) {
        constexpr int C = bstart(B) + K;
        elem<4 * C + 0>(d[K][0], t[K][0], s, mse, dot, lse);
        elem<4 * C + 1>(d[K][1], t[K][1], s, mse, dot, lse);
        elem<4 * C + 2>(d[K][2], t[K][2], s, mse, dot, lse);
        elem<4 * C + 3>(d[K][3], t[K][3], s, mse, dot, lse);
        bproc<B, K + 1>(d, t, s, mse, dot, lse);
    }
}

// stage<B>: d0/t0 = batch B (oldest, process now); d1,d2 = B+1,B+2 in flight.
// Issue B+3, fence scheduler, process B, rotate.
template<int B>
__device__ __forceinline__ void stage(const f4* __restrict__ gd,
                                      const f4* __restrict__ gt,
                                      f4 (&d0)[BN], f4 (&t0)[BN],
                                      f4 (&d1)[BN], f4 (&t1)[BN],
                                      f4 (&d2)[BN], f4 (&t2)[BN],
                                      float (&s)[8],
                                      float& mse, float& dot, float& lse) {
    f4 d3[BN], t3[BN];
    if constexpr (B + 3 < NBAT) {
        bload<B + 3>(gd, gt, d3, t3);
        __builtin_amdgcn_sched_barrier(0);    // keep the issue above the compute
    }
    bproc<B>(d0, t0, s, mse, dot, lse);
    if constexpr (B + 1 < NBAT) {
        // d3/t3 for B+3 >= NBAT are never loaded NOR processed (recursion ends
        // before bproc of that slot) — dead values, no codegen.
        stage<B + 1>(gd, gt, d1, t1, d2, t2, d3, t3, s, mse, dot, lse);
    }
}

// min 2 waves/EU -> VGPR cap 256 (grid supplies exactly 8 waves/CU).
__global__ __launch_bounds__(THREADS, 2) void multiloss_main(
        const float* __restrict__ dec, const float* __restrict__ tru,
        float2* __restrict__ ws, int ngroups) {
    int g = blockIdx.x * THREADS + threadIdx.x;   // one 4-row group per thread
    float mse = 0.0f, dot = 0.0f, lse = 0.0f;
    float s[8] = {0.0f, 0.0f, 0.0f, 0.0f, 0.0f, 0.0f, 0.0f, 0.0f};
    if (g < ngroups) {
        const f4* gd = (const f4*)dec + (size_t)g * GROUP_F4;  // byte off g*1712
        const f4* gt = (const f4*)tru + (size_t)g * GROUP_F4;
        f4 ad[BN], at[BN], bd[BN], bt[BN], cd[BN], ct[BN];
        bload<0>(gd, gt, ad, at);             // prologue: 3 batches in flight
        bload<1>(gd, gt, bd, bt);
        bload<2>(gd, gt, cd, ct);
        stage<0>(gd, gt, ad, at, bd, bt, cd, ct, s, mse, dot, lse);
    }
    float ce = lse - dot;
    // 64-lane shuffle reduction; one ws slot per wave, no atomics
#pragma unroll
    for (int off = 32; off > 0; off >>= 1) {
        mse += __shfl_down(mse, off, 64);
        ce  += __shfl_down(ce,  off, 64);
    }
    int lane  = threadIdx.x & 63;
    int gwave = (blockIdx.x * THREADS + threadIdx.x) >> 6;
    if (lane == 0)
        ws[gwave] = make_float2(mse, ce);
}

__global__ __launch_bounds__(256) void multiloss_fin(
        const float2* __restrict__ ws, float* __restrict__ out,
        int nslots, float invN) {
    float m = 0.0f, c = 0.0f;
    for (int i = threadIdx.x; i < nslots; i += 256) {
        float2 v = ws[i];
        m += v.x; c += v.y;
    }
#pragma unroll
    for (int off = 32; off > 0; off >>= 1) {
        m += __shfl_down(m, off, 64);
        c += __shfl_down(c, off, 64);
    }
    __shared__ float sm[4], sc[4];
    int wid  = threadIdx.x >> 6;
    int lane = threadIdx.x & 63;
    if (lane == 0) { sm[wid] = m; sc[wid] = c; }
    __syncthreads();
    if (threadIdx.x == 0) {
        float mse = (sm[0] + sm[1] + sm[2] + sm[3]) * invN;
        float ce  = (sc[0] + sc[1] + sc[2] + sc[3]) * invN;
        out[0] = mse + ce;
        out[1] = mse;
        out[2] = ce;
    }
}

extern "C" void kernel_launch(void* const* d_in, const int* in_sizes, int n_in,
                              void* d_out, int out_size, void* d_ws, size_t ws_size,
                              hipStream_t stream) {
    const float* dec = (const float*)d_in[0];
    const float* tru = (const float*)d_in[1];
    int nrows   = in_sizes[0] / NCOLS;          // 524288
    int ngroups = nrows / ROWS_PER_GROUP;       // 131072 (exact at BATCH=524288)
    int nblocks = (ngroups + THREADS - 1) / THREADS;   // 512
    int nwaves  = nblocks * (THREADS / 64);            // 2048 slots, 16 KB ws
    float2* ws = (float2*)d_ws;
    multiloss_main<<<nblocks, THREADS, 0, stream>>>(dec, tru, ws, ngroups);
    multiloss_fin<<<1, 256, 0, stream>>>(ws, (float*)d_out, nwaves,
                                         1.0f / (float)nrows);
}